// Round 4
// baseline (110.828 us; speedup 1.0000x reference)
//
#include <hip/hip_runtime.h>

// SKA: per-pixel dynamic grouped 3x3 conv.
// x: [B=16, C=128, H=56, W=56] f32
// w: [B=16, Cw=16, 9, H=56, W=56] f32   (channel c uses weight channel c % 16)
// out[b,c,h,w] = sum_{i,j} xpad[b,c,h+i,w+j] * w[b, c%16, i*3+j, h, w], pad=1.
//
// Round 3 (resubmit — prior bench hit GPUAcquisitionTimeout): 8-wide threads
// (2x float4 per row), groups split 2-way so each thread computes 4 of the 8
// channels sharing its weights. 200704 threads.

#define SKA_B   16
#define SKA_C   128
#define SKA_CW  16
#define SKA_H   56
#define SKA_W   56
#define SKA_HW  (SKA_H * SKA_W)        // 3136
#define SKA_Q8  7                      // 8-wide chunks per row
#define SKA_GS  2                      // group split factor
#define SKA_GPT 4                      // groups per thread

__global__ __launch_bounds__(256) void ska_kernel(
    const float* __restrict__ x,
    const float* __restrict__ w,
    float* __restrict__ out)
{
    const int tid = blockIdx.x * 256 + threadIdx.x;
    // tid -> (b, cw, gs, h, q): q innermost then h, so lane address streams
    // are contiguous 32B chunks per lane for m0/m1, w, and stores.
    const int q  = tid % SKA_Q8;
    int t        = tid / SKA_Q8;
    const int h  = t % SKA_H;
    t            = t / SKA_H;
    const int gs = t % SKA_GS;
    t            = t / SKA_GS;
    const int cw = t % SKA_CW;
    const int b  = t / SKA_CW;
    // grid exact: 16*16*2*56*7 = 200704 = 784 * 256

    const int col = q * 8;
    const int hw  = h * SKA_W + col;

    // 9 taps x 8 columns of per-pixel weights (shared by this thread's 4 channels).
    const float* wp = w + ((size_t)(b * SKA_CW + cw) * 9) * SKA_HW + hw;
    float4 wa[9], wb[9];
#pragma unroll
    for (int k = 0; k < 9; ++k) {
        wa[k] = *(const float4*)(wp + (size_t)k * SKA_HW);
        wb[k] = *(const float4*)(wp + (size_t)k * SKA_HW + 4);
    }

    const bool hv0 = (h > 0);
    const bool hv2 = (h < SKA_H - 1);
    const bool lv  = (q > 0);
    const bool rv  = (q < SKA_Q8 - 1);

    // This thread's 4 channels: c = (gs*4 + gi)*16 + cw
    const float* xb = x   + ((size_t)b * SKA_C + (size_t)gs * SKA_GPT * SKA_CW + cw) * SKA_HW + hw;
    float*       ob = out + ((size_t)b * SKA_C + (size_t)gs * SKA_GPT * SKA_CW + cw) * SKA_HW + hw;

#pragma unroll
    for (int gi = 0; gi < SKA_GPT; ++gi) {
        const float* xc = xb + (size_t)gi * SKA_CW * SKA_HW;
        float4 ac0 = {0.f, 0.f, 0.f, 0.f};
        float4 ac1 = {0.f, 0.f, 0.f, 0.f};

#pragma unroll
        for (int r = 0; r < 3; ++r) {
            if (r == 0 && !hv0) continue;
            if (r == 2 && !hv2) continue;
            const float* xr = xc + (r - 1) * SKA_W;
            const float4 m0 = *(const float4*)xr;        // cols col..col+3
            const float4 m1 = *(const float4*)(xr + 4);  // cols col+4..col+7
            const float  L  = lv ? xr[-1] : 0.0f;
            const float  R  = rv ? xr[8]  : 0.0f;
            const float4 a0 = wa[3*r + 0], a1 = wa[3*r + 1], a2 = wa[3*r + 2];
            const float4 b0 = wb[3*r + 0], b1 = wb[3*r + 1], b2 = wb[3*r + 2];

            ac0.x += L    * a0.x + m0.x * a1.x + m0.y * a2.x;
            ac0.y += m0.x * a0.y + m0.y * a1.y + m0.z * a2.y;
            ac0.z += m0.y * a0.z + m0.z * a1.z + m0.w * a2.z;
            ac0.w += m0.z * a0.w + m0.w * a1.w + m1.x * a2.w;
            ac1.x += m0.w * b0.x + m1.x * b1.x + m1.y * b2.x;
            ac1.y += m1.x * b0.y + m1.y * b1.y + m1.z * b2.y;
            ac1.z += m1.y * b0.z + m1.z * b1.z + m1.w * b2.z;
            ac1.w += m1.z * b0.w + m1.w * b1.w + R    * b2.w;
        }

        float* op = ob + (size_t)gi * SKA_CW * SKA_HW;
        *(float4*)op       = ac0;
        *(float4*)(op + 4) = ac1;
    }
}

extern "C" void kernel_launch(void* const* d_in, const int* in_sizes, int n_in,
                              void* d_out, int out_size, void* d_ws, size_t ws_size,
                              hipStream_t stream) {
    const float* x = (const float*)d_in[0];
    const float* w = (const float*)d_in[1];
    float* out = (float*)d_out;

    const int total_threads = SKA_B * SKA_CW * SKA_GS * SKA_H * SKA_Q8;  // 200704
    const int block = 256;
    const int grid = total_threads / block;                              // 784

    ska_kernel<<<grid, block, 0, stream>>>(x, w, out);
}

// Round 6
// 103.349 us; speedup vs baseline: 1.0724x; 1.0724x over previous
//
#include <hip/hip_runtime.h>

// SKA: per-pixel dynamic grouped 3x3 conv.
// x: [B=16, C=128, H=56, W=56] f32
// w: [B=16, Cw=16, 9, H=56, W=56] f32   (channel c uses weight channel c % 16)
// out[b,c,h,w] = sum_{i,j} xpad[b,c,h+i,w+j] * w[b, c%16, i*3+j, h, w], pad=1.
//
// Round 6: LDS-staged tile. One block per (b, cw, group-half): 512 blocks =
// 2 per CU. Stage 4 channels of x (58 rows x 68 cols, zero halo, 4-col left
// pad for alignment) into 63KB LDS; compute phase is branch-free: 9 global
// float4 w-loads per pixel-quad (shared by 4 channels) + pure-LDS tap reads.
// x is read from HBM exactly once, all global ops are aligned float4 streams.

#define SKA_B   16
#define SKA_C   128
#define SKA_CW  16
#define SKA_H   56
#define SKA_W   56
#define SKA_HW  (SKA_H * SKA_W)        // 3136
#define CPB     4                      // channels per block
#define LROWS   58                     // 56 + top/bottom halo
#define LSTRIDE 68                     // 4-col left halo + 56 + pad; 68*4B=272B, 16B-aligned rows
#define LSLOTS  (CPB * LROWS * LSTRIDE / 4)  // 3944 float4 slots = 63,104 B

__global__ __launch_bounds__(256) void ska_kernel(
    const float* __restrict__ x,
    const float* __restrict__ w,
    float* __restrict__ out)
{
    __shared__ float lds[CPB][LROWS][LSTRIDE];

    const int tid = threadIdx.x;
    const int blk = blockIdx.x;        // 0..511
    const int gs  = blk & 1;           // group half: channels g = gs*4 .. gs*4+3
    const int cwb = blk >> 1;
    const int cw  = cwb & 15;
    const int b   = cwb >> 4;

    // Phase 0: zero all of LDS (halo included). 63KB, ~16 f4 stores/thread.
    {
        const float4 z = {0.f, 0.f, 0.f, 0.f};
        float4* lf4 = (float4*)&lds[0][0][0];
        for (int i = tid; i < LSLOTS; i += 256) lf4[i] = z;
    }
    __syncthreads();

    // Phase 1: stage x rows. Channel c = (gs*4 + ch)*16 + cw.
    // x row h -> lds row h+1, x col c -> lds col c+4. All float4-aligned.
    const float* xb = x + ((size_t)b * SKA_C + (size_t)gs * CPB * SKA_CW + cw) * SKA_HW;
    for (int i = tid; i < CPB * SKA_H * 14; i += 256) {   // 3136 float4 loads
        const int q  = i % 14;
        const int t  = i / 14;
        const int h  = t % SKA_H;
        const int ch = t / SKA_H;
        const float4 v = *(const float4*)(xb + (size_t)ch * SKA_CW * SKA_HW + h * SKA_W + 4 * q);
        *(float4*)&lds[ch][h + 1][4 * q + 4] = v;
    }
    __syncthreads();

    // Phase 2: compute. Thread handles pixel-quads (h, q) for all 4 channels.
    const float* wb = w + ((size_t)(b * SKA_CW + cw) * 9) * SKA_HW;
    float* ob = out + ((size_t)b * SKA_C + (size_t)gs * CPB * SKA_CW + cw) * SKA_HW;

    for (int i = tid; i < SKA_H * 14; i += 256) {         // 784 pixel-quads
        const int q  = i % 14;
        const int h  = i / 14;
        const int hw = h * SKA_W + 4 * q;

        // 9 per-pixel weight vectors, shared by the block's 4 channels.
        float4 wk[9];
#pragma unroll
        for (int k = 0; k < 9; ++k)
            wk[k] = *(const float4*)(wb + (size_t)k * SKA_HW + hw);

#pragma unroll
        for (int ch = 0; ch < CPB; ++ch) {
            float a0 = 0.f, a1 = 0.f, a2 = 0.f, a3 = 0.f;
#pragma unroll
            for (int r = 0; r < 3; ++r) {
                // Output row h uses x rows h-1..h+1 -> lds rows h..h+2.
                // Need lds cols (4q+3)..(4q+8); fetch (4q+2)..(4q+8).
                const float* lp = &lds[ch][h + r][4 * q + 2];
                const float2 dl = *(const float2*)lp;        // cols +2,+3 (8B-aligned)
                const float4 m  = *(const float4*)(lp + 2);  // cols +4..+7 (16B-aligned)
                const float  e  = lp[6];                     // col  +8
                const float4 w0 = wk[3 * r + 0];
                const float4 w1 = wk[3 * r + 1];
                const float4 w2 = wk[3 * r + 2];
                a0 += dl.y * w0.x + m.x * w1.x + m.y * w2.x;
                a1 += m.x  * w0.y + m.y * w1.y + m.z * w2.y;
                a2 += m.y  * w0.z + m.z * w1.z + m.w * w2.z;
                a3 += m.z  * w0.w + m.w * w1.w + e   * w2.w;
            }
            float4 o; o.x = a0; o.y = a1; o.z = a2; o.w = a3;
            *(float4*)(ob + (size_t)ch * SKA_CW * SKA_HW + hw) = o;
        }
    }
}

extern "C" void kernel_launch(void* const* d_in, const int* in_sizes, int n_in,
                              void* d_out, int out_size, void* d_ws, size_t ws_size,
                              hipStream_t stream) {
    const float* x = (const float*)d_in[0];
    const float* w = (const float*)d_in[1];
    float* out = (float*)d_out;

    const int grid = SKA_B * SKA_CW * 2;   // 512 blocks = 2 per CU
    ska_kernel<<<grid, 256, 0, stream>>>(x, w, out);
}